// Round 1
// baseline (729.191 us; speedup 1.0000x reference)
//
#include <hip/hip_runtime.h>
#include <hip/hip_bf16.h>
#include <math.h>

// MoE: B=4,S=2048 -> N=8192 tokens, D=1024, DO=1024, E=20 experts, top-2.
// Pipeline: gate_h GEMM (gelu) -> router (softmax/top2) -> scan+tilemap ->
// scatter (bucket tokens by expert) -> grouped expert GEMM + atomicAdd combine.
// Round 1: all fp32 vector FMA, correctness-first baseline.

#define N_TOK 8192
#define DIM   1024
#define DHID  256
#define DOUT  1024
#define NE    20
#define BM    64
#define BN    64
#define BK    32
// sum_e ceil(cnt_e/64) <= 16384/64 + 20 = 276 (static grid for graph capture)
#define MAX_TTILES 276

__device__ __forceinline__ float gelu_erf(float v) {
    return 0.5f * v * (1.0f + erff(v * 0.70710678118654752f));
}

// ---------------- gating hidden GEMM: h = gelu(x @ wg1 + bg1) ----------------
__global__ __launch_bounds__(256) void k_gate_h(
    const float* __restrict__ x, const float* __restrict__ wg1,
    const float* __restrict__ bg1, float* __restrict__ h) {
  __shared__ __align__(16) float Xs[BM][36];   // pad 36 -> conflict-free a-reads
  __shared__ __align__(16) float Ws[BK][BN];
  const int t  = threadIdx.x;
  const int ty = t >> 4, tx = t & 15;
  const int m0 = blockIdx.x * BM;
  const int c0 = blockIdx.y * BN;
  float acc[4][4] = {};
  for (int k0 = 0; k0 < DIM; k0 += BK) {
#pragma unroll
    for (int l = 0; l < 2; ++l) {            // stage X: 64 rows x 32 k
      int i = t + l * 256;
      int row = i >> 3, seg = i & 7;
      *(float4*)&Xs[row][seg * 4] =
          *(const float4*)(x + (size_t)(m0 + row) * DIM + k0 + seg * 4);
    }
#pragma unroll
    for (int l = 0; l < 2; ++l) {            // stage W: 32 k x 64 cols (ld=256)
      int i = t + l * 256;
      int kk = i >> 4, seg = i & 15;
      *(float4*)&Ws[kk][seg * 4] =
          *(const float4*)(wg1 + (size_t)(k0 + kk) * DHID + c0 + seg * 4);
    }
    __syncthreads();
#pragma unroll
    for (int kk = 0; kk < BK; kk += 4) {
      float4 a[4];
#pragma unroll
      for (int i = 0; i < 4; ++i) a[i] = *(const float4*)&Xs[ty * 4 + i][kk];
#pragma unroll
      for (int u = 0; u < 4; ++u) {
        float4 b = *(const float4*)&Ws[kk + u][tx * 4];
#pragma unroll
        for (int i = 0; i < 4; ++i) {
          float av = reinterpret_cast<const float*>(&a[i])[u];
          acc[i][0] += av * b.x;
          acc[i][1] += av * b.y;
          acc[i][2] += av * b.z;
          acc[i][3] += av * b.w;
        }
      }
    }
    __syncthreads();
  }
#pragma unroll
  for (int i = 0; i < 4; ++i) {
    int row = m0 + ty * 4 + i;
    int col = c0 + tx * 4;
    float4 o;
    o.x = gelu_erf(acc[i][0] + bg1[col + 0]);
    o.y = gelu_erf(acc[i][1] + bg1[col + 1]);
    o.z = gelu_erf(acc[i][2] + bg1[col + 2]);
    o.w = gelu_erf(acc[i][3] + bg1[col + 3]);
    *(float4*)&h[(size_t)row * DHID + col] = o;
  }
}

// -------- router: logits = (h@wg2+bg2)[:, :20], softmax, top-2, counts -------
__global__ __launch_bounds__(256) void k_router(
    const float* __restrict__ h, const float* __restrict__ wg2,
    const float* __restrict__ bg2, int* __restrict__ tokexp,
    float* __restrict__ tokgate, int* __restrict__ counts) {
  __shared__ float swg[DHID * NE];  // wg2 first 20 cols, [k][j] layout
  const int t = threadIdx.x;
  for (int i = t; i < DHID * NE; i += 256) {
    int k = i / NE, j = i - k * NE;
    swg[i] = wg2[(size_t)k * (2 * NE) + j];
  }
  __syncthreads();
  const int n = blockIdx.x * 256 + t;
  float s[NE];
#pragma unroll
  for (int j = 0; j < NE; ++j) s[j] = bg2[j];
  const float* hr = h + (size_t)n * DHID;
  for (int k = 0; k < DHID; k += 4) {
    float4 hv = *(const float4*)(hr + k);
#pragma unroll
    for (int u = 0; u < 4; ++u) {
      float hvu = reinterpret_cast<const float*>(&hv)[u];
      const float* w = &swg[(k + u) * NE];
#pragma unroll
      for (int j = 0; j < NE; ++j) s[j] += hvu * w[j];
    }
  }
  float m = s[0];
#pragma unroll
  for (int j = 1; j < NE; ++j) m = fmaxf(m, s[j]);
  float sum = 0.0f;
#pragma unroll
  for (int j = 0; j < NE; ++j) { s[j] = expf(s[j] - m); sum += s[j]; }
  float inv = 1.0f / sum;
#pragma unroll
  for (int j = 0; j < NE; ++j) s[j] *= inv;
  int j0 = 0; float v0 = s[0];
#pragma unroll
  for (int j = 1; j < NE; ++j) if (s[j] > v0) { v0 = s[j]; j0 = j; }
  int j1 = -1; float v1 = -1.0f;
#pragma unroll
  for (int j = 0; j < NE; ++j)
    if (j != j0 && s[j] > v1) { v1 = s[j]; j1 = j; }
  tokexp[2 * n + 0] = j0;  tokgate[2 * n + 0] = v0;
  tokexp[2 * n + 1] = j1;  tokgate[2 * n + 1] = v1;
  atomicAdd(&counts[j0], 1);
  atomicAdd(&counts[j1], 1);
}

// ------------- scan counts -> offsets/cursors + build tile map ---------------
__global__ void k_scan(const int* __restrict__ counts, int* __restrict__ offsets,
                       int* __restrict__ cursors, int4* __restrict__ tilemap,
                       int* __restrict__ ntiles) {
  if (threadIdx.x == 0 && blockIdx.x == 0) {
    int off = 0, nt = 0;
    for (int e = 0; e < NE; ++e) {
      offsets[e] = off;
      cursors[e] = off;
      int c = counts[e];
      for (int t0 = 0; t0 < c; t0 += BM) {
        tilemap[nt] = make_int4(e, off + t0, min(BM, c - t0), 0);
        ++nt;
      }
      off += c;
    }
    *ntiles = nt;
  }
}

// --------------- scatter token ids + gates into expert buckets ---------------
__global__ __launch_bounds__(256) void k_scatter(
    const int* __restrict__ tokexp, const float* __restrict__ tokgate,
    int* __restrict__ cursors, int* __restrict__ perm,
    float* __restrict__ pgate) {
  const int n = blockIdx.x * 256 + threadIdx.x;
#pragma unroll
  for (int k = 0; k < 2; ++k) {
    int e = tokexp[2 * n + k];
    int pos = atomicAdd(&cursors[e], 1);
    perm[pos] = n;
    pgate[pos] = tokgate[2 * n + k];
  }
}

// -------- grouped expert GEMM: y[tok] += g * (x[tok] @ We[e] + be[e]) --------
__global__ __launch_bounds__(256) void k_expert(
    const float* __restrict__ x, const float* __restrict__ We,
    const float* __restrict__ be, const int* __restrict__ perm,
    const float* __restrict__ pgate, const int4* __restrict__ tilemap,
    const int* __restrict__ ntiles, float* __restrict__ y) {
  if (blockIdx.x >= *ntiles) return;
  const int4 tm = tilemap[blockIdx.x];
  const int e = tm.x, rs = tm.y, cnt = tm.z;
  const int c0 = blockIdx.y * BN;
  __shared__ __align__(16) float Xs[BM][36];
  __shared__ __align__(16) float Ws[BK][BN];
  __shared__ int stok[BM];
  __shared__ float sgate[BM];
  const int t = threadIdx.x;
  if (t < BM) {
    int r = (t < cnt) ? rs + t : rs;   // clamp to a valid bucket slot
    stok[t]  = perm[r];
    sgate[t] = (t < cnt) ? pgate[rs + t] : 0.0f;
  }
  __syncthreads();
  const int ty = t >> 4, tx = t & 15;
  const float* wbase = We + (size_t)e * DIM * DOUT;
  float acc[4][4] = {};
  for (int k0 = 0; k0 < DIM; k0 += BK) {
#pragma unroll
    for (int l = 0; l < 2; ++l) {            // stage gathered X rows
      int i = t + l * 256;
      int row = i >> 3, seg = i & 7;
      const float* xr = x + (size_t)stok[row] * DIM;
      *(float4*)&Xs[row][seg * 4] = *(const float4*)(xr + k0 + seg * 4);
    }
#pragma unroll
    for (int l = 0; l < 2; ++l) {            // stage We slab (ld=1024)
      int i = t + l * 256;
      int kk = i >> 4, seg = i & 15;
      *(float4*)&Ws[kk][seg * 4] =
          *(const float4*)(wbase + (size_t)(k0 + kk) * DOUT + c0 + seg * 4);
    }
    __syncthreads();
#pragma unroll
    for (int kk = 0; kk < BK; kk += 4) {
      float4 a[4];
#pragma unroll
      for (int i = 0; i < 4; ++i) a[i] = *(const float4*)&Xs[ty * 4 + i][kk];
#pragma unroll
      for (int u = 0; u < 4; ++u) {
        float4 b = *(const float4*)&Ws[kk + u][tx * 4];
#pragma unroll
        for (int i = 0; i < 4; ++i) {
          float av = reinterpret_cast<const float*>(&a[i])[u];
          acc[i][0] += av * b.x;
          acc[i][1] += av * b.y;
          acc[i][2] += av * b.z;
          acc[i][3] += av * b.w;
        }
      }
    }
    __syncthreads();
  }
#pragma unroll
  for (int i = 0; i < 4; ++i) {
    int lr = ty * 4 + i;
    if (lr < cnt) {
      int token = stok[lr];
      float g = sgate[lr];
      float* yr = y + (size_t)token * DOUT + c0 + tx * 4;
      const float* ber = be + (size_t)e * DOUT + c0 + tx * 4;
#pragma unroll
      for (int j = 0; j < 4; ++j) {
        atomicAdd(&yr[j], g * (acc[i][j] + ber[j]));
      }
    }
  }
}

extern "C" void kernel_launch(void* const* d_in, const int* in_sizes, int n_in,
                              void* d_out, int out_size, void* d_ws, size_t ws_size,
                              hipStream_t stream) {
  (void)in_sizes; (void)n_in; (void)ws_size;
  const float* x   = (const float*)d_in[0];
  const float* wg1 = (const float*)d_in[1];
  const float* bg1 = (const float*)d_in[2];
  const float* wg2 = (const float*)d_in[3];
  const float* bg2 = (const float*)d_in[4];
  const float* We  = (const float*)d_in[5];
  const float* be  = (const float*)d_in[6];
  float* y = (float*)d_out;

  char* ws = (char*)d_ws;
  float* h       = (float*)ws;                       // 8192*256 f32 = 8 MB
  int*   counts  = (int*)(ws + (size_t)N_TOK * DHID * 4);
  int*   offsets = counts + 32;
  int*   cursors = counts + 64;
  int*   ntiles  = counts + 96;
  int*   tokexp  = counts + 128;                     // 16384 ints
  float* tokgate = (float*)(tokexp + 2 * N_TOK);     // 16384 f32
  int*   perm    = (int*)(tokgate + 2 * N_TOK);      // 16384 ints
  float* pgate   = (float*)(perm + 2 * N_TOK);       // 16384 f32
  int4*  tilemap = (int4*)(pgate + 2 * N_TOK);       // <=276 int4

  hipMemsetAsync(counts, 0, 128 * sizeof(int), stream);
  hipMemsetAsync(y, 0, (size_t)out_size * sizeof(float), stream);

  k_gate_h<<<dim3(N_TOK / BM, DHID / BN), 256, 0, stream>>>(x, wg1, bg1, h);
  k_router<<<dim3(N_TOK / 256), 256, 0, stream>>>(h, wg2, bg2, tokexp, tokgate, counts);
  k_scan<<<1, 64, 0, stream>>>(counts, offsets, cursors, tilemap, ntiles);
  k_scatter<<<dim3(N_TOK / 256), 256, 0, stream>>>(tokexp, tokgate, cursors, perm, pgate);
  k_expert<<<dim3(MAX_TTILES, DOUT / BN), 256, 0, stream>>>(
      x, We, be, perm, pgate, tilemap, ntiles, y);
}

// Round 2
// 373.399 us; speedup vs baseline: 1.9528x; 1.9528x over previous
//
#include <hip/hip_runtime.h>
#include <hip/hip_bf16.h>
#include <math.h>

// MoE: B=4,S=2048 -> N=8192 tokens, D=1024, DO=1024, E=20 experts, top-2.
// R2: expert GEMM moved to bf16 MFMA (16x16x32), x/We pre-converted to bf16
// (We transposed to [e][n][k] so both MFMA fragments are contiguous-k reads),
// XOR-swizzled LDS tiles (T2). Router/gating stay fp32 (routing stability).

#define N_TOK 8192
#define DIM   1024
#define DHID  256
#define DOUT  1024
#define NE    20
#define BM    64
#define BN    128
// sum_e ceil(cnt_e/64) <= 16384/64 + 20 = 276 (static grid for graph capture)
#define MAX_TTILES 276

typedef __attribute__((ext_vector_type(8))) short bf16x8;
typedef __attribute__((ext_vector_type(4))) float f32x4;

__device__ __forceinline__ float gelu_erf(float v) {
    return 0.5f * v * (1.0f + erff(v * 0.70710678118654752f));
}

__device__ __forceinline__ ushort f2b(float f) {
  union { float f; uint u; } c; c.f = f;
  uint r = (c.u + 0x7FFFu + ((c.u >> 16) & 1u)) >> 16;  // round-nearest-even
  return (ushort)r;
}

// ------------------------- x fp32 -> bf16 (elementwise) ----------------------
__global__ __launch_bounds__(256) void k_cvt_x(const float* __restrict__ x,
                                               ushort* __restrict__ xb) {
  const size_t i0 = ((size_t)blockIdx.x * 256 + threadIdx.x) * 8;
  float4 a = *(const float4*)(x + i0);
  float4 b = *(const float4*)(x + i0 + 4);
  ushort o[8] = {f2b(a.x), f2b(a.y), f2b(a.z), f2b(a.w),
                 f2b(b.x), f2b(b.y), f2b(b.z), f2b(b.w)};
  *(uint4*)(xb + i0) = *(const uint4*)o;
}

// ------------- We [e][k][n] fp32 -> WeT [e][n][k] bf16 (transpose) -----------
__global__ __launch_bounds__(256) void k_cvt_weT(const float* __restrict__ We,
                                                 ushort* __restrict__ weT) {
  __shared__ ushort Ts[64][72];   // [n_local][k_local], pad 72 (144B rows, 16-aligned)
  const int e  = blockIdx.z;
  const int k0 = blockIdx.x * 64;
  const int n0 = blockIdx.y * 64;
  const int t  = threadIdx.x;
  const float* src = We + ((size_t)e << 20);
#pragma unroll
  for (int it = 0; it < 4; ++it) {          // read 16 k-rows per pass, coalesced on n
    int kk = it * 16 + (t >> 4);
    int nn = (t & 15) * 4;
    float4 v = *(const float4*)(src + (size_t)(k0 + kk) * DOUT + n0 + nn);
    Ts[nn + 0][kk] = f2b(v.x);
    Ts[nn + 1][kk] = f2b(v.y);
    Ts[nn + 2][kk] = f2b(v.z);
    Ts[nn + 3][kk] = f2b(v.w);
  }
  __syncthreads();
  ushort* dst = weT + ((size_t)e << 20);
#pragma unroll
  for (int it = 0; it < 2; ++it) {          // write 32 n-rows per pass, coalesced on k
    int nn = it * 32 + (t >> 3);
    int ks = (t & 7) * 8;
    *(uint4*)(dst + (size_t)(n0 + nn) * DIM + k0 + ks) = *(const uint4*)&Ts[nn][ks];
  }
}

// ---------------- gating hidden GEMM: h = gelu(x @ wg1 + bg1) ----------------
__global__ __launch_bounds__(256) void k_gate_h(
    const float* __restrict__ x, const float* __restrict__ wg1,
    const float* __restrict__ bg1, float* __restrict__ h) {
  __shared__ __align__(16) float Xs[64][36];
  __shared__ __align__(16) float Ws[32][64];
  const int t  = threadIdx.x;
  const int ty = t >> 4, tx = t & 15;
  const int m0 = blockIdx.x * 64;
  const int c0 = blockIdx.y * 64;
  float acc[4][4] = {};
  for (int k0 = 0; k0 < DIM; k0 += 32) {
#pragma unroll
    for (int l = 0; l < 2; ++l) {
      int i = t + l * 256;
      int row = i >> 3, seg = i & 7;
      *(float4*)&Xs[row][seg * 4] =
          *(const float4*)(x + (size_t)(m0 + row) * DIM + k0 + seg * 4);
    }
#pragma unroll
    for (int l = 0; l < 2; ++l) {
      int i = t + l * 256;
      int kk = i >> 4, seg = i & 15;
      *(float4*)&Ws[kk][seg * 4] =
          *(const float4*)(wg1 + (size_t)(k0 + kk) * DHID + c0 + seg * 4);
    }
    __syncthreads();
#pragma unroll
    for (int kk = 0; kk < 32; kk += 4) {
      float4 a[4];
#pragma unroll
      for (int i = 0; i < 4; ++i) a[i] = *(const float4*)&Xs[ty * 4 + i][kk];
#pragma unroll
      for (int u = 0; u < 4; ++u) {
        float4 b = *(const float4*)&Ws[kk + u][tx * 4];
#pragma unroll
        for (int i = 0; i < 4; ++i) {
          float av = reinterpret_cast<const float*>(&a[i])[u];
          acc[i][0] += av * b.x;
          acc[i][1] += av * b.y;
          acc[i][2] += av * b.z;
          acc[i][3] += av * b.w;
        }
      }
    }
    __syncthreads();
  }
#pragma unroll
  for (int i = 0; i < 4; ++i) {
    int row = m0 + ty * 4 + i;
    int col = c0 + tx * 4;
    float4 o;
    o.x = gelu_erf(acc[i][0] + bg1[col + 0]);
    o.y = gelu_erf(acc[i][1] + bg1[col + 1]);
    o.z = gelu_erf(acc[i][2] + bg1[col + 2]);
    o.w = gelu_erf(acc[i][3] + bg1[col + 3]);
    *(float4*)&h[(size_t)row * DHID + col] = o;
  }
}

// -------- router: logits = (h@wg2+bg2)[:, :20], softmax, top-2, counts -------
__global__ __launch_bounds__(256) void k_router(
    const float* __restrict__ h, const float* __restrict__ wg2,
    const float* __restrict__ bg2, int* __restrict__ tokexp,
    float* __restrict__ tokgate, int* __restrict__ counts) {
  __shared__ float swg[DHID * NE];
  const int t = threadIdx.x;
  for (int i = t; i < DHID * NE; i += 256) {
    int k = i / NE, j = i - k * NE;
    swg[i] = wg2[(size_t)k * (2 * NE) + j];
  }
  __syncthreads();
  const int n = blockIdx.x * 256 + t;
  float s[NE];
#pragma unroll
  for (int j = 0; j < NE; ++j) s[j] = bg2[j];
  const float* hr = h + (size_t)n * DHID;
  for (int k = 0; k < DHID; k += 4) {
    float4 hv = *(const float4*)(hr + k);
#pragma unroll
    for (int u = 0; u < 4; ++u) {
      float hvu = reinterpret_cast<const float*>(&hv)[u];
      const float* w = &swg[(k + u) * NE];
#pragma unroll
      for (int j = 0; j < NE; ++j) s[j] += hvu * w[j];
    }
  }
  float m = s[0];
#pragma unroll
  for (int j = 1; j < NE; ++j) m = fmaxf(m, s[j]);
  float sum = 0.0f;
#pragma unroll
  for (int j = 0; j < NE; ++j) { s[j] = expf(s[j] - m); sum += s[j]; }
  float inv = 1.0f / sum;
#pragma unroll
  for (int j = 0; j < NE; ++j) s[j] *= inv;
  int j0 = 0; float v0 = s[0];
#pragma unroll
  for (int j = 1; j < NE; ++j) if (s[j] > v0) { v0 = s[j]; j0 = j; }
  int j1 = -1; float v1 = -1.0f;
#pragma unroll
  for (int j = 0; j < NE; ++j)
    if (j != j0 && s[j] > v1) { v1 = s[j]; j1 = j; }
  tokexp[2 * n + 0] = j0;  tokgate[2 * n + 0] = v0;
  tokexp[2 * n + 1] = j1;  tokgate[2 * n + 1] = v1;
  atomicAdd(&counts[j0], 1);
  atomicAdd(&counts[j1], 1);
}

// ------------- scan counts -> offsets/cursors + build tile map ---------------
__global__ void k_scan(const int* __restrict__ counts, int* __restrict__ offsets,
                       int* __restrict__ cursors, int4* __restrict__ tilemap,
                       int* __restrict__ ntiles) {
  if (threadIdx.x == 0 && blockIdx.x == 0) {
    int off = 0, nt = 0;
    for (int e = 0; e < NE; ++e) {
      offsets[e] = off;
      cursors[e] = off;
      int c = counts[e];
      for (int t0 = 0; t0 < c; t0 += BM) {
        tilemap[nt] = make_int4(e, off + t0, min(BM, c - t0), 0);
        ++nt;
      }
      off += c;
    }
    *ntiles = nt;
  }
}

// --------------- scatter token ids + gates into expert buckets ---------------
__global__ __launch_bounds__(256) void k_scatter(
    const int* __restrict__ tokexp, const float* __restrict__ tokgate,
    int* __restrict__ cursors, int* __restrict__ perm,
    float* __restrict__ pgate) {
  const int n = blockIdx.x * 256 + threadIdx.x;
#pragma unroll
  for (int k = 0; k < 2; ++k) {
    int e = tokexp[2 * n + k];
    int pos = atomicAdd(&cursors[e], 1);
    perm[pos] = n;
    pgate[pos] = tokgate[2 * n + k];
  }
}

// ------ grouped expert GEMM (bf16 MFMA): y[tok] += g*(x[tok]@We[e]+be[e]) ----
// 64x128 tile, 4 waves (2x2), each wave 32x64 = 2x4 frags of 16x16x32.
__global__ __launch_bounds__(256) void k_expert(
    const ushort* __restrict__ xb, const ushort* __restrict__ weT,
    const float* __restrict__ be, const int* __restrict__ perm,
    const float* __restrict__ pgate, const int4* __restrict__ tilemap,
    const int* __restrict__ ntiles, float* __restrict__ y) {
  if (blockIdx.x >= *ntiles) return;
  const int4 tm = tilemap[blockIdx.x];
  const int e = tm.x, rs = tm.y, cnt = tm.z;
  const int c0 = blockIdx.y * BN;
  __shared__ ushort Xs[64 * 64];    // swizzled [row][k], 8 KB
  __shared__ ushort Bs[128 * 64];   // swizzled [n][k], 16 KB
  __shared__ int   stok[BM];
  __shared__ float sgate[BM];
  const int t = threadIdx.x;
  if (t < BM) {
    int r = (t < cnt) ? rs + t : rs;
    stok[t]  = perm[r];
    sgate[t] = (t < cnt) ? pgate[rs + t] : 0.0f;
  }
  __syncthreads();
  const int lane = t & 63, w = t >> 6;
  const int wr = w >> 1, wc = w & 1;
  const int lr = lane & 15, hi = lane >> 4;
  const size_t wbase = ((size_t)e << 20) + (size_t)c0 * DIM;  // weT[e][c0][0]
  char* xs = (char*)Xs;
  char* bs = (char*)Bs;
  f32x4 acc[2][4] = {};
  for (int k0 = 0; k0 < DIM; k0 += 64) {
#pragma unroll
    for (int l = 0; l < 2; ++l) {   // stage A: 512 x 16B segs (gathered rows)
      int s = t + l * 256;
      int row = s >> 3, seg = s & 7;
      uint4 v = *(const uint4*)(xb + (size_t)stok[row] * DIM + k0 + seg * 8);
      *(uint4*)(xs + row * 128 + ((seg * 16) ^ ((row & 7) << 4))) = v;
    }
#pragma unroll
    for (int l = 0; l < 4; ++l) {   // stage B: 1024 x 16B segs (WeT rows)
      int s = t + l * 256;
      int n = s >> 3, seg = s & 7;
      uint4 v = *(const uint4*)(weT + wbase + (size_t)n * DIM + k0 + seg * 8);
      *(uint4*)(bs + n * 128 + ((seg * 16) ^ ((n & 7) << 4))) = v;
    }
    __syncthreads();
#pragma unroll
    for (int ks = 0; ks < 2; ++ks) {
      const int kb = ks * 64 + hi * 16;
      bf16x8 af[2], bfr[4];
#pragma unroll
      for (int mi = 0; mi < 2; ++mi) {
        int row = wr * 32 + mi * 16 + lr;
        af[mi] = *(const bf16x8*)(xs + row * 128 + (kb ^ ((row & 7) << 4)));
      }
#pragma unroll
      for (int ni = 0; ni < 4; ++ni) {
        int n = wc * 64 + ni * 16 + lr;
        bfr[ni] = *(const bf16x8*)(bs + n * 128 + (kb ^ ((n & 7) << 4)));
      }
#pragma unroll
      for (int mi = 0; mi < 2; ++mi)
#pragma unroll
        for (int ni = 0; ni < 4; ++ni)
          acc[mi][ni] = __builtin_amdgcn_mfma_f32_16x16x32_bf16(
              af[mi], bfr[ni], acc[mi][ni], 0, 0, 0);
    }
    __syncthreads();
  }
  float bcol[4];
#pragma unroll
  for (int ni = 0; ni < 4; ++ni)
    bcol[ni] = be[(size_t)e * DOUT + c0 + wc * 64 + ni * 16 + lr];
#pragma unroll
  for (int mi = 0; mi < 2; ++mi) {
#pragma unroll
    for (int r = 0; r < 4; ++r) {
      int lrow = wr * 32 + mi * 16 + hi * 4 + r;   // C/D: col=lane&15, row=(lane>>4)*4+reg
      if (lrow < cnt) {
        int token = stok[lrow];
        float g = sgate[lrow];
        float* yr = y + (size_t)token * DOUT + c0 + wc * 64;
#pragma unroll
        for (int ni = 0; ni < 4; ++ni)
          atomicAdd(yr + ni * 16 + lr, g * (acc[mi][ni][r] + bcol[ni]));
      }
    }
  }
}

extern "C" void kernel_launch(void* const* d_in, const int* in_sizes, int n_in,
                              void* d_out, int out_size, void* d_ws, size_t ws_size,
                              hipStream_t stream) {
  (void)in_sizes; (void)n_in; (void)ws_size;
  const float* x   = (const float*)d_in[0];
  const float* wg1 = (const float*)d_in[1];
  const float* bg1 = (const float*)d_in[2];
  const float* wg2 = (const float*)d_in[3];
  const float* bg2 = (const float*)d_in[4];
  const float* We  = (const float*)d_in[5];
  const float* be  = (const float*)d_in[6];
  float* y = (float*)d_out;

  char* ws = (char*)d_ws;
  float*  h    = (float*)ws;                                   // 8 MB
  ushort* xb   = (ushort*)(ws + (size_t)N_TOK * DHID * 4);     // 16 MB
  ushort* weT  = (ushort*)((char*)xb + (size_t)N_TOK * DIM * 2);  // 40 MB
  char*   ctrl = (char*)weT + (size_t)NE * DIM * DOUT * 2;
  int*   counts  = (int*)ctrl;
  int*   offsets = counts + 32;
  int*   cursors = counts + 64;
  int*   ntiles  = counts + 96;
  int*   tokexp  = counts + 128;
  float* tokgate = (float*)(tokexp + 2 * N_TOK);
  int*   perm    = (int*)(tokgate + 2 * N_TOK);
  float* pgate   = (float*)(perm + 2 * N_TOK);
  int4*  tilemap = (int4*)(pgate + 2 * N_TOK);

  hipMemsetAsync(counts, 0, 128 * sizeof(int), stream);
  hipMemsetAsync(y, 0, (size_t)out_size * sizeof(float), stream);

  k_cvt_x<<<dim3(N_TOK * DIM / (256 * 8)), 256, 0, stream>>>(x, xb);
  k_cvt_weT<<<dim3(16, 16, NE), 256, 0, stream>>>(We, weT);
  k_gate_h<<<dim3(N_TOK / 64, DHID / 64), 256, 0, stream>>>(x, wg1, bg1, h);
  k_router<<<dim3(N_TOK / 256), 256, 0, stream>>>(h, wg2, bg2, tokexp, tokgate, counts);
  k_scan<<<1, 64, 0, stream>>>(counts, offsets, cursors, tilemap, ntiles);
  k_scatter<<<dim3(N_TOK / 256), 256, 0, stream>>>(tokexp, tokgate, cursors, perm, pgate);
  k_expert<<<dim3(MAX_TTILES, DOUT / BN), 256, 0, stream>>>(
      xb, weT, be, perm, pgate, tilemap, ntiles, y);
}

// Round 3
// 352.694 us; speedup vs baseline: 2.0675x; 1.0587x over previous
//
#include <hip/hip_runtime.h>
#include <hip/hip_bf16.h>
#include <math.h>

// MoE: B=4,S=2048 -> N=8192 tokens, D=1024, DO=1024, E=20 experts, top-2.
// R3: k_expert -> m97-style 128x128 tile, BK=64, global_load_lds(16B) with
// pre-swizzled global source (linear LDS dest + XOR-swz read). cvt kernels
// fused into k_front alongside the fp32 gate GEMM (block-partitioned).

#define N_TOK 8192
#define DIM   1024
#define DHID  256
#define DOUT  1024
#define NE    20
#define BM2   128
#define BN2   128
#define BK2   64
// sum_e ceil(cnt_e/128) <= 16384/128 + 20 = 148
#define MAX_TT 148

typedef __attribute__((ext_vector_type(8))) short bf16x8;
typedef __attribute__((ext_vector_type(4))) float f32x4;

__device__ __forceinline__ float gelu_erf(float v) {
    return 0.5f * v * (1.0f + erff(v * 0.70710678118654752f));
}

__device__ __forceinline__ ushort f2b(float f) {
  union { float f; uint u; } c; c.f = f;
  uint r = (c.u + 0x7FFFu + ((c.u >> 16) & 1u)) >> 16;  // RNE
  return (ushort)r;
}

// ============ k_front: [0,512) gate GEMM | [512,5632) We->bf16T | [5632,7680) x->bf16
__global__ __launch_bounds__(256) void k_front(
    const float* __restrict__ x, const float* __restrict__ wg1,
    const float* __restrict__ bg1, float* __restrict__ h,
    const float* __restrict__ We, ushort* __restrict__ weT,
    ushort* __restrict__ xb) {
  __shared__ __align__(16) char smem[17408];
  const int bid = blockIdx.x;
  const int t = threadIdx.x;

  if (bid < 512) {
    // ---- gating GEMM: h = gelu(x @ wg1 + bg1), 64x64 tile, fp32 ----
    float (*Xs)[36] = (float(*)[36])smem;                  // 9216 B
    float (*Ws)[64] = (float(*)[64])(smem + 9216);         // 8192 B
    const int ty = t >> 4, tx = t & 15;
    const int m0 = (bid >> 2) * 64;
    const int c0 = (bid & 3) * 64;
    float acc[4][4] = {};
    for (int k0 = 0; k0 < DIM; k0 += 32) {
#pragma unroll
      for (int l = 0; l < 2; ++l) {
        int i = t + l * 256;
        int row = i >> 3, seg = i & 7;
        *(float4*)&Xs[row][seg * 4] =
            *(const float4*)(x + (size_t)(m0 + row) * DIM + k0 + seg * 4);
      }
#pragma unroll
      for (int l = 0; l < 2; ++l) {
        int i = t + l * 256;
        int kk = i >> 4, seg = i & 15;
        *(float4*)&Ws[kk][seg * 4] =
            *(const float4*)(wg1 + (size_t)(k0 + kk) * DHID + c0 + seg * 4);
      }
      __syncthreads();
#pragma unroll
      for (int kk = 0; kk < 32; kk += 4) {
        float4 a[4];
#pragma unroll
        for (int i = 0; i < 4; ++i) a[i] = *(const float4*)&Xs[ty * 4 + i][kk];
#pragma unroll
        for (int u = 0; u < 4; ++u) {
          float4 b = *(const float4*)&Ws[kk + u][tx * 4];
#pragma unroll
          for (int i = 0; i < 4; ++i) {
            float av = reinterpret_cast<const float*>(&a[i])[u];
            acc[i][0] += av * b.x;
            acc[i][1] += av * b.y;
            acc[i][2] += av * b.z;
            acc[i][3] += av * b.w;
          }
        }
      }
      __syncthreads();
    }
#pragma unroll
    for (int i = 0; i < 4; ++i) {
      int row = m0 + ty * 4 + i;
      int col = c0 + tx * 4;
      float4 o;
      o.x = gelu_erf(acc[i][0] + bg1[col + 0]);
      o.y = gelu_erf(acc[i][1] + bg1[col + 1]);
      o.z = gelu_erf(acc[i][2] + bg1[col + 2]);
      o.w = gelu_erf(acc[i][3] + bg1[col + 3]);
      *(float4*)&h[(size_t)row * DHID + col] = o;
    }
  } else if (bid < 5632) {
    // ---- We [e][k][n] fp32 -> weT [e][n][k] bf16 ----
    ushort (*Ts)[72] = (ushort(*)[72])smem;                // 9216 B
    const int b = bid - 512;
    const int e = b >> 8, rem = b & 255;
    const int k0 = (rem >> 4) * 64;
    const int n0 = (rem & 15) * 64;
    const float* src = We + ((size_t)e << 20);
#pragma unroll
    for (int it = 0; it < 4; ++it) {
      int kk = it * 16 + (t >> 4);
      int nn = (t & 15) * 4;
      float4 v = *(const float4*)(src + (size_t)(k0 + kk) * DOUT + n0 + nn);
      Ts[nn + 0][kk] = f2b(v.x);
      Ts[nn + 1][kk] = f2b(v.y);
      Ts[nn + 2][kk] = f2b(v.z);
      Ts[nn + 3][kk] = f2b(v.w);
    }
    __syncthreads();
    ushort* dst = weT + ((size_t)e << 20);
#pragma unroll
    for (int it = 0; it < 2; ++it) {
      int nn = it * 32 + (t >> 3);
      int ks = (t & 7) * 8;
      *(uint4*)(dst + (size_t)(n0 + nn) * DIM + k0 + ks) = *(const uint4*)&Ts[nn][ks];
    }
  } else {
    // ---- x fp32 -> bf16, 16 elems/thread ----
    const size_t i0 = (((size_t)(bid - 5632)) * 256 + t) * 16;
    ushort o[16];
#pragma unroll
    for (int j = 0; j < 4; ++j) {
      float4 v = *(const float4*)(x + i0 + j * 4);
      o[j * 4 + 0] = f2b(v.x); o[j * 4 + 1] = f2b(v.y);
      o[j * 4 + 2] = f2b(v.z); o[j * 4 + 3] = f2b(v.w);
    }
    *(uint4*)(xb + i0)     = *(const uint4*)&o[0];
    *(uint4*)(xb + i0 + 8) = *(const uint4*)&o[8];
  }
}

// -------- router: logits = (h@wg2+bg2)[:, :20], softmax, top-2, counts -------
__global__ __launch_bounds__(256) void k_router(
    const float* __restrict__ h, const float* __restrict__ wg2,
    const float* __restrict__ bg2, int* __restrict__ tokexp,
    float* __restrict__ tokgate, int* __restrict__ counts) {
  __shared__ float swg[DHID * NE];
  const int t = threadIdx.x;
  for (int i = t; i < DHID * NE; i += 256) {
    int k = i / NE, j = i - k * NE;
    swg[i] = wg2[(size_t)k * (2 * NE) + j];
  }
  __syncthreads();
  const int n = blockIdx.x * 256 + t;
  float s[NE];
#pragma unroll
  for (int j = 0; j < NE; ++j) s[j] = bg2[j];
  const float* hr = h + (size_t)n * DHID;
  for (int k = 0; k < DHID; k += 4) {
    float4 hv = *(const float4*)(hr + k);
#pragma unroll
    for (int u = 0; u < 4; ++u) {
      float hvu = reinterpret_cast<const float*>(&hv)[u];
      const float* w = &swg[(k + u) * NE];
#pragma unroll
      for (int j = 0; j < NE; ++j) s[j] += hvu * w[j];
    }
  }
  float m = s[0];
#pragma unroll
  for (int j = 1; j < NE; ++j) m = fmaxf(m, s[j]);
  float sum = 0.0f;
#pragma unroll
  for (int j = 0; j < NE; ++j) { s[j] = expf(s[j] - m); sum += s[j]; }
  float inv = 1.0f / sum;
#pragma unroll
  for (int j = 0; j < NE; ++j) s[j] *= inv;
  int j0 = 0; float v0 = s[0];
#pragma unroll
  for (int j = 1; j < NE; ++j) if (s[j] > v0) { v0 = s[j]; j0 = j; }
  int j1 = -1; float v1 = -1.0f;
#pragma unroll
  for (int j = 0; j < NE; ++j)
    if (j != j0 && s[j] > v1) { v1 = s[j]; j1 = j; }
  tokexp[2 * n + 0] = j0;  tokgate[2 * n + 0] = v0;
  tokexp[2 * n + 1] = j1;  tokgate[2 * n + 1] = v1;
  atomicAdd(&counts[j0], 1);
  atomicAdd(&counts[j1], 1);
}

// --------- scan (1 wave): prefix over counts + tile starts, tilemap ----------
__global__ void k_scan(const int* __restrict__ counts, int* __restrict__ offsets,
                       int* __restrict__ cursors, int4* __restrict__ tilemap,
                       int* __restrict__ ntiles) {
  const int lane = threadIdx.x;
  int c  = (lane < NE) ? counts[lane] : 0;
  int nt = (c + BM2 - 1) >> 7;
  int cs = c, ts = nt;
  for (int d = 1; d < 64; d <<= 1) {
    int u = __shfl_up(cs, d); if (lane >= d) cs += u;
    int v = __shfl_up(ts, d); if (lane >= d) ts += v;
  }
  int coff = cs - c;
  int toff = ts - nt;
  if (lane < NE) {
    offsets[lane] = coff;
    cursors[lane] = coff;
    for (int i = 0; i < nt; ++i)
      tilemap[toff + i] = make_int4(lane, coff + i * BM2, min(BM2, c - i * BM2), 0);
  }
  if (lane == 63) *ntiles = ts;
}

// --------------- scatter token ids + gates into expert buckets ---------------
__global__ __launch_bounds__(256) void k_scatter(
    const int* __restrict__ tokexp, const float* __restrict__ tokgate,
    int* __restrict__ cursors, int* __restrict__ perm,
    float* __restrict__ pgate) {
  const int n = blockIdx.x * 256 + threadIdx.x;
#pragma unroll
  for (int k = 0; k < 2; ++k) {
    int e = tokexp[2 * n + k];
    int pos = atomicAdd(&cursors[e], 1);
    perm[pos] = n;
    pgate[pos] = tokgate[2 * n + k];
  }
}

// ------ grouped expert GEMM (bf16 MFMA): y[tok] += g*(x[tok]@We[e]+be[e]) ----
// 128x128 tile, BK=64, 4 waves (2x2), per-wave 64x64 = 4x4 frags of 16x16x32.
// global_load_lds 16B, linear LDS dest, source pre-XOR-swizzled (involution).
__global__ __launch_bounds__(256) void k_expert(
    const ushort* __restrict__ xb, const ushort* __restrict__ weT,
    const float* __restrict__ be, const int* __restrict__ perm,
    const float* __restrict__ pgate, const int4* __restrict__ tilemap,
    const int* __restrict__ ntiles, float* __restrict__ y) {
  if (blockIdx.x >= *ntiles) return;
  const int4 tm = tilemap[blockIdx.x];
  const int e = tm.x, rs = tm.y, cnt = tm.z;
  const int c0 = blockIdx.y * BN2;
  __shared__ __align__(1024) ushort As[BM2 * BK2];   // 16 KB, rows of 128 B
  __shared__ __align__(1024) ushort Bs[BN2 * BK2];   // 16 KB
  __shared__ int   stok[BM2];
  __shared__ float sgate[BM2];
  const int t = threadIdx.x;
  if (t < BM2) {
    int r = (t < cnt) ? rs + t : rs;
    stok[t]  = perm[r];
    sgate[t] = (t < cnt) ? pgate[rs + t] : 0.0f;
  }
  __syncthreads();
  const int lane = t & 63, w = t >> 6;
  const int wr = w >> 1, wc = w & 1;
  const int lr = lane & 15, hi = lane >> 4;
  const int srow = lane >> 3, sseg = lane & 7;

  // per-lane pre-swizzled global sources (+BK2 ushorts per k-step)
  const ushort* asrc[4];
  const ushort* bsrc[4];
  ushort* adst[4];
  ushort* bdst[4];
#pragma unroll
  for (int l = 0; l < 4; ++l) {
    int r = w * 32 + l * 8 + srow;                    // covers 0..127
    asrc[l] = xb + (size_t)stok[r] * DIM + ((sseg ^ (r & 7)) << 3);
    adst[l] = As + (w * 32 + l * 8) * BK2;
    bsrc[l] = weT + ((size_t)e << 20) + (size_t)(c0 + r) * DIM + ((sseg ^ (r & 7)) << 3);
    bdst[l] = Bs + (w * 32 + l * 8) * BK2;
  }

  const char* Ab = (const char*)As;
  const char* Bb = (const char*)Bs;
  f32x4 acc[4][4] = {};
  for (int k0 = 0; k0 < DIM; k0 += BK2) {
#pragma unroll
    for (int l = 0; l < 4; ++l)
      __builtin_amdgcn_global_load_lds(asrc[l] + k0, adst[l], 16, 0, 0);
#pragma unroll
    for (int l = 0; l < 4; ++l)
      __builtin_amdgcn_global_load_lds(bsrc[l] + k0, bdst[l], 16, 0, 0);
    __syncthreads();   // compiler emits vmcnt(0) drain here (m97 structure)
#pragma unroll
    for (int ks = 0; ks < 2; ++ks) {
      const int kb = ks * 64 + hi * 16;
      bf16x8 af[4], bfr[4];
#pragma unroll
      for (int mi = 0; mi < 4; ++mi) {
        int r = wr * 64 + mi * 16 + lr;
        af[mi] = *(const bf16x8*)(Ab + r * 128 + (kb ^ ((r & 7) << 4)));
      }
#pragma unroll
      for (int ni = 0; ni < 4; ++ni) {
        int n = wc * 64 + ni * 16 + lr;
        bfr[ni] = *(const bf16x8*)(Bb + n * 128 + (kb ^ ((n & 7) << 4)));
      }
#pragma unroll
      for (int mi = 0; mi < 4; ++mi)
#pragma unroll
        for (int ni = 0; ni < 4; ++ni)
          acc[mi][ni] = __builtin_amdgcn_mfma_f32_16x16x32_bf16(
              af[mi], bfr[ni], acc[mi][ni], 0, 0, 0);
    }
    __syncthreads();
  }
  float bcol[4];
#pragma unroll
  for (int ni = 0; ni < 4; ++ni)
    bcol[ni] = be[(size_t)e * DOUT + c0 + wc * 64 + ni * 16 + lr];
#pragma unroll
  for (int mi = 0; mi < 4; ++mi) {
#pragma unroll
    for (int r = 0; r < 4; ++r) {
      int lrow = wr * 64 + mi * 16 + hi * 4 + r;  // C/D: col=lane&15, row=(lane>>4)*4+reg
      if (lrow < cnt) {
        int token = stok[lrow];
        float g = sgate[lrow];
        float* yr = y + (size_t)token * DOUT + c0 + wc * 64;
#pragma unroll
        for (int ni = 0; ni < 4; ++ni)
          atomicAdd(yr + ni * 16 + lr, g * (acc[mi][ni][r] + bcol[ni]));
      }
    }
  }
}

extern "C" void kernel_launch(void* const* d_in, const int* in_sizes, int n_in,
                              void* d_out, int out_size, void* d_ws, size_t ws_size,
                              hipStream_t stream) {
  (void)in_sizes; (void)n_in; (void)ws_size;
  const float* x   = (const float*)d_in[0];
  const float* wg1 = (const float*)d_in[1];
  const float* bg1 = (const float*)d_in[2];
  const float* wg2 = (const float*)d_in[3];
  const float* bg2 = (const float*)d_in[4];
  const float* We  = (const float*)d_in[5];
  const float* be  = (const float*)d_in[6];
  float* y = (float*)d_out;

  char* ws = (char*)d_ws;
  float*  h    = (float*)ws;                                      // 8 MB
  ushort* xb   = (ushort*)(ws + (size_t)N_TOK * DHID * 4);        // 16 MB
  ushort* weT  = (ushort*)((char*)xb + (size_t)N_TOK * DIM * 2);  // 40 MB
  char*   ctrl = (char*)weT + (size_t)NE * DIM * DOUT * 2;
  int*   counts  = (int*)ctrl;
  int*   offsets = counts + 32;
  int*   cursors = counts + 64;
  int*   ntiles  = counts + 96;
  int*   tokexp  = counts + 128;
  float* tokgate = (float*)(tokexp + 2 * N_TOK);
  int*   perm    = (int*)(tokgate + 2 * N_TOK);
  float* pgate   = (float*)(perm + 2 * N_TOK);
  int4*  tilemap = (int4*)(pgate + 2 * N_TOK);

  hipMemsetAsync(counts, 0, 128 * sizeof(int), stream);
  hipMemsetAsync(y, 0, (size_t)out_size * sizeof(float), stream);

  k_front<<<dim3(512 + 5120 + 2048), 256, 0, stream>>>(x, wg1, bg1, h, We, weT, xb);
  k_router<<<dim3(N_TOK / 256), 256, 0, stream>>>(h, wg2, bg2, tokexp, tokgate, counts);
  k_scan<<<1, 64, 0, stream>>>(counts, offsets, cursors, tilemap, ntiles);
  k_scatter<<<dim3(N_TOK / 256), 256, 0, stream>>>(tokexp, tokgate, cursors, perm, pgate);
  k_expert<<<dim3(MAX_TT, DOUT / BN2), 256, 0, stream>>>(
      xb, weT, be, perm, pgate, tilemap, ntiles, y);
}

// Round 4
// 310.166 us; speedup vs baseline: 2.3510x; 1.1371x over previous
//
#include <hip/hip_runtime.h>
#include <hip/hip_bf16.h>
#include <math.h>

// MoE: B=4,S=2048 -> N=8192 tokens, D=1024, DO=1024, E=20 experts, top-2.
// R4: atomic-free combine. k_expert writes g*(x@We+be) as bf16 into a dense
// contrib[16384][1024] buffer (LDS-transposed, coalesced uint4 stores);
// k_reduce sums each token's 2 contributions. XCD-chunked block swizzle.

#define N_TOK 8192
#define DIM   1024
#define DHID  256
#define DOUT  1024
#define NE    20
#define BM2   128
#define BN2   128
#define BK2   64
// sum_e ceil(cnt_e/128) <= 16384/128 + 20 = 148
#define MAX_TT 148

typedef __attribute__((ext_vector_type(8))) short bf16x8;
typedef __attribute__((ext_vector_type(4))) float f32x4;

__device__ __forceinline__ float gelu_erf(float v) {
    return 0.5f * v * (1.0f + erff(v * 0.70710678118654752f));
}

__device__ __forceinline__ ushort f2b(float f) {
  union { float f; uint u; } c; c.f = f;
  uint r = (c.u + 0x7FFFu + ((c.u >> 16) & 1u)) >> 16;  // RNE
  return (ushort)r;
}

__device__ __forceinline__ float b2f(ushort u) {
  union { uint u; float f; } c; c.u = ((uint)u) << 16;
  return c.f;
}

// ============ k_front: [0,512) gate GEMM | [512,5632) We->bf16T | [5632,7680) x->bf16
__global__ __launch_bounds__(256) void k_front(
    const float* __restrict__ x, const float* __restrict__ wg1,
    const float* __restrict__ bg1, float* __restrict__ h,
    const float* __restrict__ We, ushort* __restrict__ weT,
    ushort* __restrict__ xb) {
  __shared__ __align__(16) char smem[17408];
  const int bid = blockIdx.x;
  const int t = threadIdx.x;

  if (bid < 512) {
    // ---- gating GEMM: h = gelu(x @ wg1 + bg1), 64x64 tile, fp32 ----
    float (*Xs)[36] = (float(*)[36])smem;                  // 9216 B
    float (*Ws)[64] = (float(*)[64])(smem + 9216);         // 8192 B
    const int ty = t >> 4, tx = t & 15;
    const int m0 = (bid >> 2) * 64;
    const int c0 = (bid & 3) * 64;
    float acc[4][4] = {};
    for (int k0 = 0; k0 < DIM; k0 += 32) {
#pragma unroll
      for (int l = 0; l < 2; ++l) {
        int i = t + l * 256;
        int row = i >> 3, seg = i & 7;
        *(float4*)&Xs[row][seg * 4] =
            *(const float4*)(x + (size_t)(m0 + row) * DIM + k0 + seg * 4);
      }
#pragma unroll
      for (int l = 0; l < 2; ++l) {
        int i = t + l * 256;
        int kk = i >> 4, seg = i & 15;
        *(float4*)&Ws[kk][seg * 4] =
            *(const float4*)(wg1 + (size_t)(k0 + kk) * DHID + c0 + seg * 4);
      }
      __syncthreads();
#pragma unroll
      for (int kk = 0; kk < 32; kk += 4) {
        float4 a[4];
#pragma unroll
        for (int i = 0; i < 4; ++i) a[i] = *(const float4*)&Xs[ty * 4 + i][kk];
#pragma unroll
        for (int u = 0; u < 4; ++u) {
          float4 b = *(const float4*)&Ws[kk + u][tx * 4];
#pragma unroll
          for (int i = 0; i < 4; ++i) {
            float av = reinterpret_cast<const float*>(&a[i])[u];
            acc[i][0] += av * b.x;
            acc[i][1] += av * b.y;
            acc[i][2] += av * b.z;
            acc[i][3] += av * b.w;
          }
        }
      }
      __syncthreads();
    }
#pragma unroll
    for (int i = 0; i < 4; ++i) {
      int row = m0 + ty * 4 + i;
      int col = c0 + tx * 4;
      float4 o;
      o.x = gelu_erf(acc[i][0] + bg1[col + 0]);
      o.y = gelu_erf(acc[i][1] + bg1[col + 1]);
      o.z = gelu_erf(acc[i][2] + bg1[col + 2]);
      o.w = gelu_erf(acc[i][3] + bg1[col + 3]);
      *(float4*)&h[(size_t)row * DHID + col] = o;
    }
  } else if (bid < 5632) {
    // ---- We [e][k][n] fp32 -> weT [e][n][k] bf16 ----
    ushort (*Ts)[72] = (ushort(*)[72])smem;                // 9216 B
    const int b = bid - 512;
    const int e = b >> 8, rem = b & 255;
    const int k0 = (rem >> 4) * 64;
    const int n0 = (rem & 15) * 64;
    const float* src = We + ((size_t)e << 20);
#pragma unroll
    for (int it = 0; it < 4; ++it) {
      int kk = it * 16 + (t >> 4);
      int nn = (t & 15) * 4;
      float4 v = *(const float4*)(src + (size_t)(k0 + kk) * DOUT + n0 + nn);
      Ts[nn + 0][kk] = f2b(v.x);
      Ts[nn + 1][kk] = f2b(v.y);
      Ts[nn + 2][kk] = f2b(v.z);
      Ts[nn + 3][kk] = f2b(v.w);
    }
    __syncthreads();
    ushort* dst = weT + ((size_t)e << 20);
#pragma unroll
    for (int it = 0; it < 2; ++it) {
      int nn = it * 32 + (t >> 3);
      int ks = (t & 7) * 8;
      *(uint4*)(dst + (size_t)(n0 + nn) * DIM + k0 + ks) = *(const uint4*)&Ts[nn][ks];
    }
  } else {
    // ---- x fp32 -> bf16, 16 elems/thread ----
    const size_t i0 = (((size_t)(bid - 5632)) * 256 + t) * 16;
    ushort o[16];
#pragma unroll
    for (int j = 0; j < 4; ++j) {
      float4 v = *(const float4*)(x + i0 + j * 4);
      o[j * 4 + 0] = f2b(v.x); o[j * 4 + 1] = f2b(v.y);
      o[j * 4 + 2] = f2b(v.z); o[j * 4 + 3] = f2b(v.w);
    }
    *(uint4*)(xb + i0)     = *(const uint4*)&o[0];
    *(uint4*)(xb + i0 + 8) = *(const uint4*)&o[8];
  }
}

// -------- router: logits = (h@wg2+bg2)[:, :20], softmax, top-2, counts -------
__global__ __launch_bounds__(256) void k_router(
    const float* __restrict__ h, const float* __restrict__ wg2,
    const float* __restrict__ bg2, int* __restrict__ tokexp,
    float* __restrict__ tokgate, int* __restrict__ counts) {
  __shared__ float swg[DHID * NE];
  const int t = threadIdx.x;
  for (int i = t; i < DHID * NE; i += 256) {
    int k = i / NE, j = i - k * NE;
    swg[i] = wg2[(size_t)k * (2 * NE) + j];
  }
  __syncthreads();
  const int n = blockIdx.x * 256 + t;
  float s[NE];
#pragma unroll
  for (int j = 0; j < NE; ++j) s[j] = bg2[j];
  const float* hr = h + (size_t)n * DHID;
  for (int k = 0; k < DHID; k += 4) {
    float4 hv = *(const float4*)(hr + k);
#pragma unroll
    for (int u = 0; u < 4; ++u) {
      float hvu = reinterpret_cast<const float*>(&hv)[u];
      const float* w = &swg[(k + u) * NE];
#pragma unroll
      for (int j = 0; j < NE; ++j) s[j] += hvu * w[j];
    }
  }
  float m = s[0];
#pragma unroll
  for (int j = 1; j < NE; ++j) m = fmaxf(m, s[j]);
  float sum = 0.0f;
#pragma unroll
  for (int j = 0; j < NE; ++j) { s[j] = expf(s[j] - m); sum += s[j]; }
  float inv = 1.0f / sum;
#pragma unroll
  for (int j = 0; j < NE; ++j) s[j] *= inv;
  int j0 = 0; float v0 = s[0];
#pragma unroll
  for (int j = 1; j < NE; ++j) if (s[j] > v0) { v0 = s[j]; j0 = j; }
  int j1 = -1; float v1 = -1.0f;
#pragma unroll
  for (int j = 0; j < NE; ++j)
    if (j != j0 && s[j] > v1) { v1 = s[j]; j1 = j; }
  tokexp[2 * n + 0] = j0;  tokgate[2 * n + 0] = v0;
  tokexp[2 * n + 1] = j1;  tokgate[2 * n + 1] = v1;
  atomicAdd(&counts[j0], 1);
  atomicAdd(&counts[j1], 1);
}

// --------- scan (1 wave): prefix over counts + tile starts, tilemap ----------
__global__ void k_scan(const int* __restrict__ counts, int* __restrict__ offsets,
                       int* __restrict__ cursors, int4* __restrict__ tilemap,
                       int* __restrict__ ntiles) {
  const int lane = threadIdx.x;
  int c  = (lane < NE) ? counts[lane] : 0;
  int nt = (c + BM2 - 1) >> 7;
  int cs = c, ts = nt;
  for (int d = 1; d < 64; d <<= 1) {
    int u = __shfl_up(cs, d); if (lane >= d) cs += u;
    int v = __shfl_up(ts, d); if (lane >= d) ts += v;
  }
  int coff = cs - c;
  int toff = ts - nt;
  if (lane < NE) {
    offsets[lane] = coff;
    cursors[lane] = coff;
    for (int i = 0; i < nt; ++i)
      tilemap[toff + i] = make_int4(lane, coff + i * BM2, min(BM2, c - i * BM2), 0);
  }
  if (lane == 63) *ntiles = ts;
}

// ------ scatter token ids + gates into buckets; record inverse mapping -------
__global__ __launch_bounds__(256) void k_scatter(
    const int* __restrict__ tokexp, const float* __restrict__ tokgate,
    int* __restrict__ cursors, int* __restrict__ perm,
    float* __restrict__ pgate, int* __restrict__ inv) {
  const int n = blockIdx.x * 256 + threadIdx.x;
#pragma unroll
  for (int k = 0; k < 2; ++k) {
    int e = tokexp[2 * n + k];
    int pos = atomicAdd(&cursors[e], 1);
    perm[pos] = n;
    pgate[pos] = tokgate[2 * n + k];
    inv[2 * n + k] = pos;
  }
}

// ------ grouped expert GEMM (bf16 MFMA): contrib[pos] = g*(x@We[e]+be[e]) ----
// 128x128 tile, BK=64, 4 waves (2x2), per-wave 64x64 = 4x4 frags of 16x16x32.
// global_load_lds 16B (linear dest + pre-XOR'd source + XOR'd read).
// Epilogue: bf16 via per-wave LDS transpose -> coalesced uint4 stores.
__global__ __launch_bounds__(256) void k_expert(
    const ushort* __restrict__ xb, const ushort* __restrict__ weT,
    const float* __restrict__ be, const int* __restrict__ perm,
    const float* __restrict__ pgate, const int4* __restrict__ tilemap,
    const int* __restrict__ ntiles, ushort* __restrict__ contrib) {
  // XCD-chunked swizzle: 1184 blocks = 8 XCDs x 148; each XCD gets a
  // contiguous run of row-tiles across all 8 col panels.
  const int lin = blockIdx.x + blockIdx.y * MAX_TT;
  const int nt8 = (lin & 7) * MAX_TT + (lin >> 3);
  const int rt = nt8 >> 3, pn = nt8 & 7;
  if (rt >= *ntiles) return;
  const int4 tm = tilemap[rt];
  const int e = tm.x, rs = tm.y, cnt = tm.z;
  const int c0 = pn * BN2;

  __shared__ __align__(1024) char smem[37888];
  int*    stok  = (int*)smem;               // 512 B
  float*  sgate = (float*)(smem + 512);     // 512 B
  ushort* As    = (ushort*)(smem + 1024);   // 16 KB  [128][64]
  ushort* Bs    = (ushort*)(smem + 17408);  // 16 KB  [128][64]

  const int t = threadIdx.x;
  if (t < BM2) {
    int r = (t < cnt) ? rs + t : rs;
    stok[t]  = perm[r];
    sgate[t] = (t < cnt) ? pgate[rs + t] : 0.0f;
  }
  __syncthreads();
  const int lane = t & 63, w = t >> 6;
  const int wr = w >> 1, wc = w & 1;
  const int lr = lane & 15, hi = lane >> 4;
  const int srow = lane >> 3, sseg = lane & 7;

  const ushort* asrc[4];
  const ushort* bsrc[4];
  ushort* adst[4];
  ushort* bdst[4];
#pragma unroll
  for (int l = 0; l < 4; ++l) {
    int r = w * 32 + l * 8 + srow;                    // 0..127
    asrc[l] = xb + (size_t)stok[r] * DIM + ((sseg ^ (r & 7)) << 3);
    adst[l] = As + (w * 32 + l * 8) * BK2;
    bsrc[l] = weT + ((size_t)e << 20) + (size_t)(c0 + r) * DIM + ((sseg ^ (r & 7)) << 3);
    bdst[l] = Bs + (w * 32 + l * 8) * BK2;
  }

  const char* Ab = (const char*)As;
  const char* Bb = (const char*)Bs;
  f32x4 acc[4][4] = {};
  for (int k0 = 0; k0 < DIM; k0 += BK2) {
#pragma unroll
    for (int l = 0; l < 4; ++l)
      __builtin_amdgcn_global_load_lds(asrc[l] + k0, adst[l], 16, 0, 0);
#pragma unroll
    for (int l = 0; l < 4; ++l)
      __builtin_amdgcn_global_load_lds(bsrc[l] + k0, bdst[l], 16, 0, 0);
    __syncthreads();
#pragma unroll
    for (int ks = 0; ks < 2; ++ks) {
      const int kb = ks * 64 + hi * 16;
      bf16x8 af[4], bfr[4];
#pragma unroll
      for (int mi = 0; mi < 4; ++mi) {
        int r = wr * 64 + mi * 16 + lr;
        af[mi] = *(const bf16x8*)(Ab + r * 128 + (kb ^ ((r & 7) << 4)));
      }
#pragma unroll
      for (int ni = 0; ni < 4; ++ni) {
        int n = wc * 64 + ni * 16 + lr;
        bfr[ni] = *(const bf16x8*)(Bb + n * 128 + (kb ^ ((n & 7) << 4)));
      }
#pragma unroll
      for (int mi = 0; mi < 4; ++mi)
#pragma unroll
        for (int ni = 0; ni < 4; ++ni)
          acc[mi][ni] = __builtin_amdgcn_mfma_f32_16x16x32_bf16(
              af[mi], bfr[ni], acc[mi][ni], 0, 0, 0);
    }
    __syncthreads();
  }

  // ---- epilogue: gate+bias in fp32, bf16 LDS transpose, uint4 stores ----
  ushort (*Ep)[72] = (ushort(*)[72])(smem + 1024 + w * 9216);  // [64][72]
  float bcol[4];
#pragma unroll
  for (int ni = 0; ni < 4; ++ni)
    bcol[ni] = be[(size_t)e * DOUT + c0 + wc * 64 + ni * 16 + lr];
#pragma unroll
  for (int mi = 0; mi < 4; ++mi)
#pragma unroll
    for (int r = 0; r < 4; ++r) {
      int rowl = mi * 16 + hi * 4 + r;      // C/D: col=lane&15, row=(lane>>4)*4+reg
      float g = sgate[wr * 64 + rowl];
#pragma unroll
      for (int ni = 0; ni < 4; ++ni)
        Ep[rowl][ni * 16 + lr] = f2b(g * (acc[mi][ni][r] + bcol[ni]));
    }
  __syncthreads();
#pragma unroll
  for (int it = 0; it < 8; ++it) {
    int rowl = it * 8 + (lane >> 3);
    int slotL = wr * 64 + rowl;
    if (slotL < cnt) {
      uint4 v = *(const uint4*)&Ep[rowl][(lane & 7) * 8];
      *(uint4*)(contrib + (size_t)(rs + slotL) * DOUT + c0 + wc * 64 + (lane & 7) * 8) = v;
    }
  }
}

// --------- reduce: y[n] = contrib[inv[2n]] + contrib[inv[2n+1]] --------------
__global__ __launch_bounds__(256) void k_reduce(
    const ushort* __restrict__ contrib, const int* __restrict__ inv,
    float* __restrict__ y) {
  const int t = threadIdx.x;
  const int n = blockIdx.x * 2 + (t >> 7);
  const int c = (t & 127) * 8;
  const int p0 = inv[2 * n], p1 = inv[2 * n + 1];
  uint4 a = *(const uint4*)(contrib + (size_t)p0 * DOUT + c);
  uint4 b = *(const uint4*)(contrib + (size_t)p1 * DOUT + c);
  const ushort* ua = (const ushort*)&a;
  const ushort* ub = (const ushort*)&b;
  float4 o0, o1;
  o0.x = b2f(ua[0]) + b2f(ub[0]);
  o0.y = b2f(ua[1]) + b2f(ub[1]);
  o0.z = b2f(ua[2]) + b2f(ub[2]);
  o0.w = b2f(ua[3]) + b2f(ub[3]);
  o1.x = b2f(ua[4]) + b2f(ub[4]);
  o1.y = b2f(ua[5]) + b2f(ub[5]);
  o1.z = b2f(ua[6]) + b2f(ub[6]);
  o1.w = b2f(ua[7]) + b2f(ub[7]);
  float* yr = y + (size_t)n * DOUT + c;
  *(float4*)yr = o0;
  *(float4*)(yr + 4) = o1;
}

extern "C" void kernel_launch(void* const* d_in, const int* in_sizes, int n_in,
                              void* d_out, int out_size, void* d_ws, size_t ws_size,
                              hipStream_t stream) {
  (void)in_sizes; (void)n_in; (void)ws_size; (void)out_size;
  const float* x   = (const float*)d_in[0];
  const float* wg1 = (const float*)d_in[1];
  const float* bg1 = (const float*)d_in[2];
  const float* wg2 = (const float*)d_in[3];
  const float* bg2 = (const float*)d_in[4];
  const float* We  = (const float*)d_in[5];
  const float* be  = (const float*)d_in[6];
  float* y = (float*)d_out;

  char* ws = (char*)d_ws;
  float*  h       = (float*)ws;                                      // 8 MB
  ushort* xb      = (ushort*)(ws + (size_t)N_TOK * DHID * 4);        // 16 MB
  ushort* weT     = (ushort*)((char*)xb + (size_t)N_TOK * DIM * 2);  // 40 MB
  ushort* contrib = (ushort*)((char*)weT + (size_t)NE * DIM * DOUT * 2);  // 32 MB
  char*   ctrl    = (char*)contrib + (size_t)2 * N_TOK * DOUT * 2;
  int*   counts  = (int*)ctrl;
  int*   offsets = counts + 32;
  int*   cursors = counts + 64;
  int*   ntiles  = counts + 96;
  int*   tokexp  = counts + 128;
  float* tokgate = (float*)(tokexp + 2 * N_TOK);
  int*   perm    = (int*)(tokgate + 2 * N_TOK);
  float* pgate   = (float*)(perm + 2 * N_TOK);
  int*   inv     = (int*)(pgate + 2 * N_TOK);
  int4*  tilemap = (int4*)(inv + 2 * N_TOK);

  hipMemsetAsync(counts, 0, 128 * sizeof(int), stream);

  k_front<<<dim3(512 + 5120 + 2048), 256, 0, stream>>>(x, wg1, bg1, h, We, weT, xb);
  k_router<<<dim3(N_TOK / 256), 256, 0, stream>>>(h, wg2, bg2, tokexp, tokgate, counts);
  k_scan<<<1, 64, 0, stream>>>(counts, offsets, cursors, tilemap, ntiles);
  k_scatter<<<dim3(N_TOK / 256), 256, 0, stream>>>(tokexp, tokgate, cursors, perm, pgate, inv);
  k_expert<<<dim3(MAX_TT, DOUT / BN2), 256, 0, stream>>>(
      xb, weT, be, perm, pgate, tilemap, ntiles, contrib);
  k_reduce<<<dim3(N_TOK / 2), 256, 0, stream>>>(contrib, inv, y);
}